// Round 1
// baseline (192.423 us; speedup 1.0000x reference)
//
#include <hip/hip_runtime.h>

#define VOCAB 32000
#define NROWS 4096
#define IGNORE_INDEX (-100)

// ---------------------------------------------------------------------------
// Kernel 1: one block per row. Computes
//   row_loss[r] = mask(r) * 0.5 * sum_j [ p*(lp-lm) + q*(lq-lm) ],
//   p = exp(lp), q = exp(lq), m = 0.5*(p+q), lm = log(m)   (BETA = 0.5)
// Fully deterministic: fixed-order per-thread accumulation + fixed-shape
// shuffle/LDS tree reduction.
// ---------------------------------------------------------------------------
__global__ __launch_bounds__(256) void jsd_rows_kernel(
    const float* __restrict__ log_q,
    const float* __restrict__ log_p,
    const int* __restrict__ label,
    float* __restrict__ row_loss) {
  const int row = blockIdx.x;
  const float4* lp4 = reinterpret_cast<const float4*>(log_p) + (size_t)row * (VOCAB / 4);
  const float4* lq4 = reinterpret_cast<const float4*>(log_q) + (size_t)row * (VOCAB / 4);

  float acc = 0.0f;
  for (int i = threadIdx.x; i < VOCAB / 4; i += 256) {
    float4 lp = lp4[i];
    float4 lq = lq4[i];
    const float* lpc = reinterpret_cast<const float*>(&lp);
    const float* lqc = reinterpret_cast<const float*>(&lq);
#pragma unroll
    for (int c = 0; c < 4; ++c) {
      float lpv = lpc[c];
      float lqv = lqc[c];
      float p = __expf(lpv);
      float q = __expf(lqv);
      float m = 0.5f * (p + q);
      float lm = __logf(m);
      acc += p * (lpv - lm) + q * (lqv - lm);
    }
  }

  // wave64 shuffle reduce
#pragma unroll
  for (int off = 32; off > 0; off >>= 1) acc += __shfl_down(acc, off, 64);

  __shared__ float smem[4];
  const int lane = threadIdx.x & 63;
  const int wid = threadIdx.x >> 6;
  if (lane == 0) smem[wid] = acc;
  __syncthreads();
  if (threadIdx.x == 0) {
    float total = smem[0] + smem[1] + smem[2] + smem[3];
    bool valid = (label[row] != IGNORE_INDEX);
    row_loss[row] = valid ? 0.5f * total : 0.0f;
  }
}

// ---------------------------------------------------------------------------
// Kernel 2: single block; deterministic reduce of the 4096 row losses and
// the valid-label count; writes mean to d_out[0].
// ---------------------------------------------------------------------------
__global__ __launch_bounds__(256) void jsd_finalize_kernel(
    const float* __restrict__ row_loss,
    const int* __restrict__ label,
    float* __restrict__ out) {
  float sum = 0.0f;
  int cnt = 0;
  for (int i = threadIdx.x; i < NROWS; i += 256) {
    sum += row_loss[i];
    cnt += (label[i] != IGNORE_INDEX) ? 1 : 0;
  }
#pragma unroll
  for (int off = 32; off > 0; off >>= 1) {
    sum += __shfl_down(sum, off, 64);
    cnt += __shfl_down(cnt, off, 64);
  }
  __shared__ float ssum[4];
  __shared__ int scnt[4];
  const int lane = threadIdx.x & 63;
  const int wid = threadIdx.x >> 6;
  if (lane == 0) { ssum[wid] = sum; scnt[wid] = cnt; }
  __syncthreads();
  if (threadIdx.x == 0) {
    float total = ssum[0] + ssum[1] + ssum[2] + ssum[3];
    int n = scnt[0] + scnt[1] + scnt[2] + scnt[3];
    out[0] = (n > 0) ? total / fmaxf((float)n, 1.0f) : 0.0f;
  }
}

extern "C" void kernel_launch(void* const* d_in, const int* in_sizes, int n_in,
                              void* d_out, int out_size, void* d_ws, size_t ws_size,
                              hipStream_t stream) {
  const float* log_q = (const float*)d_in[0];
  const float* log_p = (const float*)d_in[1];
  const int* label = (const int*)d_in[2];
  float* out = (float*)d_out;
  float* row_loss = (float*)d_ws;  // NROWS floats

  jsd_rows_kernel<<<NROWS, 256, 0, stream>>>(log_q, log_p, label, row_loss);
  jsd_finalize_kernel<<<1, 256, 0, stream>>>(row_loss, label, out);
}